// Round 14
// baseline (300.943 us; speedup 1.0000x reference)
//
#include <hip/hip_runtime.h>
#include <hip/hip_bf16.h>

typedef _Float16 f16;
typedef _Float16 f16x4 __attribute__((ext_vector_type(4)));
typedef _Float16 f16x8 __attribute__((ext_vector_type(8)));
typedef float f32x4 __attribute__((ext_vector_type(4)));

#define DEV static __device__ __forceinline__

DEV void gld_lds16(const void* g, void* l) {
  __builtin_amdgcn_global_load_lds(
      (const __attribute__((address_space(1))) void*)g,
      (__attribute__((address_space(3))) void*)l, 16, 0, 0);
}

DEV float fast_tanh(float x) {
  float e = __expf(2.0f * x);
  return 1.0f - 2.0f / (e + 1.0f);
}

DEV int xcd_swizzle(int raw, int nwg) {
  return ((nwg & 7) == 0) ? ((raw & 7) * (nwg >> 3) + (raw >> 3)) : raw;
}

// ---------------- x (f32) -> xh (f16) ----------------
__global__ __launch_bounds__(256) void k_cvt_x(const float* __restrict__ x,
                                               f16* __restrict__ xh, long n) {
  long i0 = ((long)blockIdx.x * 256 + threadIdx.x) * 4;
  long stride = (long)gridDim.x * 1024;
  for (long i = i0; i < n; i += stride) {
    const float4 v = *(const float4*)(x + i);
    f16x4 h;
    h.x = (f16)v.x; h.y = (f16)v.y; h.z = (f16)v.z; h.w = (f16)v.w;
    *(f16x4*)(xh + i) = h;
  }
}

// ---------------- transpose with secondary z-slice (z >= zSplit -> set 2)
// W [K][N] f32 -> Wt [N][K] f16, optional col-scale 1/std[k]
__global__ __launch_bounds__(256) void k_transpose2(
    const float* __restrict__ in, f16* __restrict__ out,
    const float* __restrict__ stdv, int K_, int N_,
    const float* __restrict__ in2, f16* __restrict__ out2,
    const float* __restrict__ stdv2, int K2, int N2, int zSplit) {
  __shared__ float tile[32][33];
  const int z = blockIdx.z;
  const float* inp; f16* outp; const float* sd; int KK, NN;
  if (z >= zSplit) {
    inp = in2; outp = out2; sd = stdv2; KK = K2; NN = N2;
  } else {
    inp = in + (long)z * K_ * N_; outp = out + (long)z * K_ * N_;
    sd = stdv ? stdv + (long)z * K_ : nullptr; KK = K_; NN = N_;
  }
  const int n0 = blockIdx.x * 32, k0 = blockIdx.y * 32;
  if (n0 >= NN || k0 >= KK) return;   // block-uniform
  const int tx = threadIdx.x, ty = threadIdx.y;
#pragma unroll
  for (int j = 0; j < 4; j++)
    tile[ty + j * 8][tx] = inp[(long)(k0 + ty + j * 8) * NN + n0 + tx];
  __syncthreads();
  const float rs = sd ? 1.0f / sd[k0 + tx] : 1.0f;
#pragma unroll
  for (int j = 0; j < 4; j++)
    outp[(long)(n0 + ty + j * 8) * KK + k0 + tx] = (f16)(tile[tx][ty + j * 8] * rs);
}

// ---------------- plain transpose (for eWa) ----------------
__global__ __launch_bounds__(256) void k_transpose(const float* __restrict__ in,
                                                   f16* __restrict__ out,
                                                   const float* __restrict__ stdv,
                                                   int K_, int N_) {
  __shared__ float tile[32][33];
  const int e = blockIdx.z;
  const float* ine = in + (long)e * K_ * N_;
  f16* oute = out + (long)e * K_ * N_;
  const int n0 = blockIdx.x * 32, k0 = blockIdx.y * 32;
  const int tx = threadIdx.x, ty = threadIdx.y;
#pragma unroll
  for (int j = 0; j < 4; j++)
    tile[ty + j * 8][tx] = ine[(long)(k0 + ty + j * 8) * N_ + n0 + tx];
  __syncthreads();
  const float rs = stdv ? 1.0f / stdv[(long)e * K_ + k0 + tx] : 1.0f;
#pragma unroll
  for (int j = 0; j < 4; j++)
    oute[(long)(n0 + ty + j * 8) * K_ + k0 + tx] = (f16)(tile[tx][ty + j * 8] * rs);
}

// ---------------- corrected bias, merged: grid (x, z); z < zSplit -> expert z, else gating
__global__ __launch_bounds__(1024) void k_bias_corr2(
    const float* __restrict__ W, const float* __restrict__ b,
    const float* __restrict__ mean, const float* __restrict__ stdv,
    float* __restrict__ outb, int S_, int H_,
    const float* __restrict__ W2, const float* __restrict__ b2,
    const float* __restrict__ mean2, const float* __restrict__ std2,
    float* __restrict__ outb2, int H2, int zSplit) {
  __shared__ float red[16][64];
  const int z = blockIdx.y;
  const float* Wp; const float* bp; const float* mp; const float* sp;
  float* op; int HH;
  if (z >= zSplit) {
    if ((int)(blockIdx.x * 64) >= H2) return;
    Wp = W2; bp = b2; mp = mean2; sp = std2; op = outb2; HH = H2;
  } else {
    Wp = W + (long)z * S_ * H_; bp = b + (long)z * H_;
    mp = mean + (long)z * S_; sp = stdv + (long)z * S_;
    op = outb + (long)z * H_; HH = H_;
  }
  const int h = blockIdx.x * 64 + threadIdx.x;
  const int sl = threadIdx.y;
  float acc = 0.0f;
#pragma unroll 4
  for (int s = sl; s < S_; s += 16) acc += (mp[s] / sp[s]) * Wp[(long)s * HH + h];
  red[sl][threadIdx.x] = acc;
  __syncthreads();
  if (sl == 0) {
    float a = 0.0f;
#pragma unroll
    for (int j = 0; j < 16; j++) a += red[j][threadIdx.x];
    op[h] = bp[h] - a;
  }
}

// ---------------- 128x128 GEMM, BK=64, counted-vmcnt pipeline (R11, proven; fallback path).
__global__ __launch_bounds__(256) void k_gemm_cv(
    const f16* __restrict__ A, const f16* __restrict__ Bt,
    const float* __restrict__ bias, f16* __restrict__ C,
    int M, int K, int lda, int ldb, int ldc,
    long sA, long sB, long sBias, long sC) {
  A += (long)blockIdx.z * sA; Bt += (long)blockIdx.z * sB;
  bias += (long)blockIdx.z * sBias; C += (long)blockIdx.z * sC;
  extern __shared__ __align__(16) f16 lds[];
  const int tid = threadIdx.x, wave = tid >> 6, lane = tid & 63;
  const int nwg = gridDim.x * gridDim.y;
  const int logical = xcd_swizzle(blockIdx.y * gridDim.x + blockIdx.x, nwg);
  const int bx = logical % gridDim.x, by = logical / gridDim.x;
  const int m0 = by * 128, n0 = bx * 128;
  const int wr = wave >> 1, wc = wave & 1;
  f32x4 acc[4][4] = {};
  const int swz = (tid & 7) ^ ((tid >> 3) & 7);
  const f16* Ag = A + (long)(m0 + (tid >> 3)) * lda + swz * 8;
  const f16* Bg = Bt + (long)(n0 + (tid >> 3)) * ldb + swz * 8;
  const int wo = wave * 512;

#define STG_A(bufi, tile)                                         \
  { f16* _d = lds + (bufi) * 8192 + wo;                           \
    const long _k = (long)(tile) << 6;                            \
    gld_lds16(Ag + _k, _d);                                       \
    gld_lds16(Ag + (long)32 * lda + _k, _d + 2048);               \
    gld_lds16(Ag + (long)64 * lda + _k, _d + 4096);               \
    gld_lds16(Ag + (long)96 * lda + _k, _d + 6144); }
#define STG_B(bufi, tile)                                         \
  { f16* _d = lds + 24576 + (bufi) * 8192 + wo;                   \
    const long _k = (long)(tile) << 6;                            \
    gld_lds16(Bg + _k, _d);                                       \
    gld_lds16(Bg + (long)32 * ldb + _k, _d + 2048);               \
    gld_lds16(Bg + (long)64 * ldb + _k, _d + 4096);               \
    gld_lds16(Bg + (long)96 * ldb + _k, _d + 6144); }

  const int nt = K >> 6;
  STG_A(0, 0)
  STG_B(0, 0)
  STG_A(1, 1)
  asm volatile("s_waitcnt vmcnt(4)" ::: "memory");
  __builtin_amdgcn_s_barrier();
  asm volatile("" ::: "memory");

  for (int t = 0; t < nt; ++t) {
    if (t + 1 < nt) STG_B((t + 1) & 1, t + 1)
    if (t + 2 < nt) STG_A((t + 2) % 3, t + 2)
    const f16* Abuf = lds + (t % 3) * 8192;
    const f16* Bbuf = lds + 24576 + (t & 1) * 8192;
#pragma unroll
    for (int kk = 0; kk < 2; kk++) {
      f16x8 af[4], bfr[4];
      const int rchunk = (kk * 4 + (lane >> 4)) ^ (lane & 7);
#pragma unroll
      for (int mi = 0; mi < 4; mi++)
        af[mi] = *(const f16x8*)&Abuf[(wr * 64 + mi * 16 + (lane & 15)) * 64 + rchunk * 8];
#pragma unroll
      for (int ni = 0; ni < 4; ni++)
        bfr[ni] = *(const f16x8*)&Bbuf[(wc * 64 + ni * 16 + (lane & 15)) * 64 + rchunk * 8];
#pragma unroll
      for (int mi = 0; mi < 4; mi++)
#pragma unroll
        for (int ni = 0; ni < 4; ni++)
          acc[mi][ni] = __builtin_amdgcn_mfma_f32_16x16x32_f16(af[mi], bfr[ni], acc[mi][ni], 0, 0, 0);
    }
    if (t + 2 < nt) {
      asm volatile("s_waitcnt vmcnt(4)" ::: "memory");
    } else {
      asm volatile("s_waitcnt vmcnt(0)" ::: "memory");
    }
    __builtin_amdgcn_s_barrier();
    asm volatile("" ::: "memory");
  }
#undef STG_A
#undef STG_B

  const int r0 = (lane >> 4) * 4, cb = lane & 15;
#pragma unroll
  for (int ni = 0; ni < 4; ni++) {
    const int col = n0 + wc * 64 + ni * 16 + cb;
    const float bc = bias[col];
#pragma unroll
    for (int mi = 0; mi < 4; mi++) {
      const int row = m0 + wr * 64 + mi * 16 + r0;
#pragma unroll
      for (int r = 0; r < 4; r++)
        C[(long)(row + r) * ldc + col] = (f16)fast_tanh(acc[mi][ni][r] + bc);
    }
  }
}

// ---------------- 256x256 8-phase GEMM (R12, proven) + secondary z-slice.
// z >= zSplit uses param set 2 (gating ride-along); x-blocks >= nx2 exit.
__global__ __launch_bounds__(512, 2) void k_gemm_8p(
    const f16* __restrict__ A, const f16* __restrict__ Bt,
    const float* __restrict__ bias, f16* __restrict__ C,
    int M, int K, int lda, int ldb, int ldc,
    long sA, long sB, long sBias, long sC,
    const f16* __restrict__ A2, const f16* __restrict__ B2,
    const float* __restrict__ bias2, f16* __restrict__ C2,
    int K2, int lda2, int ldb2, int ldc2, int nx2, int zSplit) {
  extern __shared__ __align__(16) f16 lds[];
  const int tid = threadIdx.x, wave = tid >> 6, lane = tid & 63;
  const int nwg = gridDim.x * gridDim.y;
  const int logical = xcd_swizzle(blockIdx.y * gridDim.x + blockIdx.x, nwg);
  const int bx = logical % gridDim.x, by = logical / gridDim.x;
  if ((int)blockIdx.z >= zSplit) {
    if (bx >= nx2) return;
    A = A2; Bt = B2; bias = bias2; C = C2;
    K = K2; lda = lda2; ldb = ldb2; ldc = ldc2;
  } else {
    A += (long)blockIdx.z * sA; Bt += (long)blockIdx.z * sB;
    bias += (long)blockIdx.z * sBias; C += (long)blockIdx.z * sC;
  }
  const int m0 = by * 256, n0 = bx * 256;
  const int wr = wave >> 2, wc = wave & 3;
  f32x4 acc[8][4] = {};

  const int swz = (tid & 7) ^ ((tid >> 3) & 7);
  const f16* Ag = A + (long)(m0 + (tid >> 3)) * lda + swz * 8;
  const f16* Bg = Bt + (long)(n0 + (tid >> 3)) * ldb + swz * 8;
  const int tdst = tid * 8;

  const int rc0 = (lane >> 4) ^ (lane & 7);
  const int rc1 = (4 + (lane >> 4)) ^ (lane & 7);
  int aoff[8], boff[4];
#pragma unroll
  for (int mi = 0; mi < 8; mi++) aoff[mi] = (wr * 128 + mi * 16 + (lane & 15)) * 64;
#pragma unroll
  for (int ni = 0; ni < 4; ni++) boff[ni] = 16384 + (wc * 64 + ni * 16 + (lane & 15)) * 64;

#define STG_A(jt, h)                                                          \
  { f16* _d = lds + ((jt) & 1) * 32768 + (h) * 8192 + tdst;                   \
    const long _k = (long)(jt) << 6;                                          \
    gld_lds16(Ag + (long)((h) * 128) * lda + _k, _d);                         \
    gld_lds16(Ag + (long)((h) * 128 + 64) * lda + _k, _d + 4096); }
#define STG_B(jt, h)                                                          \
  { f16* _d = lds + ((jt) & 1) * 32768 + 16384 + (h) * 8192 + tdst;           \
    const long _k = (long)(jt) << 6;                                          \
    gld_lds16(Bg + (long)((h) * 128) * ldb + _k, _d);                         \
    gld_lds16(Bg + (long)((h) * 128 + 64) * ldb + _k, _d + 4096); }
#define LOAD_A(b, rc)                                                         \
  _Pragma("unroll") for (int mi = 0; mi < 8; mi++)                            \
      af[mi] = *(const f16x8*)&lds[(b) * 32768 + aoff[mi] + (rc) * 8];
#define LOAD_B(b, ni, rc)                                                     \
  bfr[ni] = *(const f16x8*)&lds[(b) * 32768 + boff[ni] + (rc) * 8];
#define MMA2(nA, nB)                                                          \
  __builtin_amdgcn_s_setprio(1);                                              \
  _Pragma("unroll") for (int mi = 0; mi < 8; mi++) {                          \
    acc[mi][nA] = __builtin_amdgcn_mfma_f32_16x16x32_f16(af[mi], bfr[nA], acc[mi][nA], 0, 0, 0); \
    acc[mi][nB] = __builtin_amdgcn_mfma_f32_16x16x32_f16(af[mi], bfr[nB], acc[mi][nB], 0, 0, 0); \
  }                                                                           \
  __builtin_amdgcn_s_setprio(0);
#define BAR()                                                                 \
  __builtin_amdgcn_s_barrier();                                               \
  asm volatile("" ::: "memory")
#define WAITL()                                                               \
  asm volatile("s_waitcnt lgkmcnt(0)" ::: "memory");                          \
  __builtin_amdgcn_sched_barrier(0)

  const int nt = K >> 6;  // nt >= 2

  STG_A(0, 0) STG_A(0, 1) STG_B(0, 0) STG_B(0, 1)
  STG_A(1, 0)
  asm volatile("s_waitcnt vmcnt(2)" ::: "memory");
  BAR();

  f16x8 af[8], bfr[4];
  for (int j = 0; j < nt; ++j) {
    const int b = j & 1;
    LOAD_A(b, rc0) LOAD_B(b, 0, rc0) LOAD_B(b, 1, rc0)
    if (j + 1 < nt) STG_A(j + 1, 1)
    BAR(); WAITL(); MMA2(0, 1) BAR();
    LOAD_B(b, 2, rc0) LOAD_B(b, 3, rc0)
    if (j + 1 < nt) STG_B(j + 1, 0)
    BAR(); WAITL(); MMA2(2, 3) BAR();
    LOAD_A(b, rc1) LOAD_B(b, 0, rc1) LOAD_B(b, 1, rc1)
    if (j + 1 < nt) STG_B(j + 1, 1)
    BAR(); WAITL(); MMA2(0, 1) BAR();
    LOAD_B(b, 2, rc1) LOAD_B(b, 3, rc1)
    if (j + 2 < nt) STG_A(j + 2, 0)
    BAR(); WAITL(); MMA2(2, 3)
    if (j + 1 < nt) {
      if (j + 2 < nt) {
        asm volatile("s_waitcnt vmcnt(2)" ::: "memory");
      } else {
        asm volatile("s_waitcnt vmcnt(0)" ::: "memory");
      }
    }
    BAR();
  }
#undef STG_A
#undef STG_B
#undef LOAD_A
#undef LOAD_B
#undef MMA2
#undef BAR
#undef WAITL

  const int r0 = (lane >> 4) * 4, cb = lane & 15;
  float bcv[4];
#pragma unroll
  for (int ni = 0; ni < 4; ni++) bcv[ni] = bias[n0 + wc * 64 + ni * 16 + cb];
#pragma unroll
  for (int mi = 0; mi < 8; mi++) {
#pragma unroll
    for (int r = 0; r < 4; r++) {
      const long row = m0 + wr * 128 + mi * 16 + r0 + r;
#pragma unroll
      for (int ni = 0; ni < 4; ni++) {
        const int col = n0 + wc * 64 + ni * 16 + cb;
        C[row * (long)ldc + col] = (f16)fast_tanh(acc[mi][ni][r] + bcv[ni]);
      }
    }
  }
}

// ---------------- gating head: logits = h1 @ gWa + gba; softmax over 4 -> gw [B,4] f32
__global__ __launch_bounds__(256) void k_gating_head(const f16* __restrict__ h1,
                                                     const float* __restrict__ gWa,
                                                     const float* __restrict__ gba,
                                                     float* __restrict__ gw, int B_) {
  const int b = blockIdx.x * 4 + (threadIdx.x >> 6);
  const int lane = threadIdx.x & 63;
  const f16x4 hv = *(const f16x4*)&h1[(long)b * 256 + lane * 4];
  float s0 = 0, s1 = 0, s2 = 0, s3 = 0;
#pragma unroll
  for (int j = 0; j < 4; j++) {
    const float hh = (float)hv[j];
    const float4 wr4 = *(const float4*)&gWa[(lane * 4 + j) * 4];
    s0 += hh * wr4.x; s1 += hh * wr4.y; s2 += hh * wr4.z; s3 += hh * wr4.w;
  }
#pragma unroll
  for (int off = 32; off >= 1; off >>= 1) {
    s0 += __shfl_xor(s0, off);
    s1 += __shfl_xor(s1, off);
    s2 += __shfl_xor(s2, off);
    s3 += __shfl_xor(s3, off);
  }
  const float l0 = s0 + gba[0], l1 = s1 + gba[1], l2 = s2 + gba[2], l3 = s3 + gba[3];
  float mx = fmaxf(fmaxf(l0, l1), fmaxf(l2, l3));
  const float e0 = __expf(l0 - mx), e1 = __expf(l1 - mx), e2 = __expf(l2 - mx), e3 = __expf(l3 - mx);
  const float inv = 1.0f / (e0 + e1 + e2 + e3);
  if (lane == 0) {
    float4 o; o.x = e0 * inv; o.y = e1 * inv; o.z = e2 * inv; o.w = e3 * inv;
    *(float4*)&gw[(long)b * 4] = o;
  }
}

// ---------------- fused head (g==4): out[b,a] = [sum_e gw[b,e]*((he1_e@Wt_e^T)[b,a]
//                  + eba[e,a])] * scale[a]; gw applied in-register per expert segment.
__global__ __launch_bounds__(256) void k_head2(const f16* __restrict__ he1,
                                               const f16* __restrict__ Wt,
                                               const float* __restrict__ eba,
                                               const float* __restrict__ scale,
                                               const float* __restrict__ gw,
                                               float* __restrict__ out,
                                               long sA) {
  constexpr int K = 512;
  __shared__ __align__(16) f16 As[2][64 * 64];
  __shared__ __align__(16) f16 Bs[2][64 * 64];
  const int tid = threadIdx.x, wave = tid >> 6, lane = tid & 63;
  const int bid = xcd_swizzle(blockIdx.x, gridDim.x);
  const long m0 = (long)bid * 64;
  const int swz = (tid & 7) ^ ((tid >> 3) & 7);
  const f16* Ag = he1 + (m0 + tid / 8) * K + swz * 8;
  const f16* Bg = Wt + (long)(tid / 8) * K + swz * 8;
  const int wo = wave * 512;
  const int r0 = (lane >> 4) * 4, cb = lane & 15;
  float4 gwv[4];
#pragma unroll
  for (int r = 0; r < 4; r++)
    gwv[r] = *(const float4*)&gw[(m0 + wave * 16 + r0 + r) * 4];
  f32x4 osum[4] = {};
  f32x4 acc[4] = {};

#pragma unroll
  for (int i = 0; i < 2; i++) {
    gld_lds16(Ag + (long)i * 32 * K, &As[0][wo + i * 2048]);
    gld_lds16(Bg + (long)i * 32 * K, &Bs[0][wo + i * 2048]);
  }
  __syncthreads();
  int cur = 0;
#pragma unroll
  for (int e = 0; e < 4; e++) {
    for (int kt = 0; kt < 8; ++kt) {
      const int s = e * 8 + kt;
      if (s + 1 < 32) {
        const int sn = s + 1;
        const long ae = (long)(sn >> 3) * sA + ((sn & 7) << 6);
        const long be = (long)(sn >> 3) * (64 * K) + ((sn & 7) << 6);
#pragma unroll
        for (int i = 0; i < 2; i++) {
          gld_lds16(Ag + ae + (long)i * 32 * K, &As[cur ^ 1][wo + i * 2048]);
          gld_lds16(Bg + be + (long)i * 32 * K, &Bs[cur ^ 1][wo + i * 2048]);
        }
      }
#pragma unroll
      for (int kk = 0; kk < 2; kk++) {
        const int rchunk = (kk * 4 + (lane >> 4)) ^ (lane & 7);
        const f16x8 a = *(const f16x8*)&As[cur][(wave * 16 + (lane & 15)) * 64 + rchunk * 8];
#pragma unroll
        for (int ni = 0; ni < 4; ni++) {
          const f16x8 bq = *(const f16x8*)&Bs[cur][(ni * 16 + (lane & 15)) * 64 + rchunk * 8];
          acc[ni] = __builtin_amdgcn_mfma_f32_16x16x32_f16(a, bq, acc[ni], 0, 0, 0);
        }
      }
      __syncthreads();
      cur ^= 1;
    }
#pragma unroll
    for (int ni = 0; ni < 4; ni++)
#pragma unroll
      for (int r = 0; r < 4; r++) {
        const float ge = (e == 0) ? gwv[r].x : (e == 1) ? gwv[r].y
                        : (e == 2) ? gwv[r].z : gwv[r].w;
        osum[ni][r] += ge * acc[ni][r];
        acc[ni][r] = 0.0f;
      }
  }

#pragma unroll
  for (int ni = 0; ni < 4; ni++) {
    const int col = ni * 16 + cb;
    const float sc = scale[col];
#pragma unroll
    for (int r = 0; r < 4; r++) {
      const long row = m0 + wave * 16 + r0 + r;
      const float b4 = gwv[r].x * eba[col] + gwv[r].y * eba[64 + col] +
                       gwv[r].z * eba[128 + col] + gwv[r].w * eba[192 + col];
      out[row * 64 + col] = (osum[ni][r] + b4) * sc;
    }
  }
}

// ---------------- per-expert head (fallback path)
__global__ __launch_bounds__(256) void k_head(const f16* __restrict__ he1,
                                              const f16* __restrict__ Wt,
                                              const float* __restrict__ ebae,
                                              const float* __restrict__ scale,
                                              const float* __restrict__ gw,
                                              float* __restrict__ outa,
                                              int e0, int K,
                                              long sA, long sB, long sBias, long sC) {
  const int z = blockIdx.z;
  he1 += (long)z * sA; Wt += (long)z * sB; ebae += (long)z * sBias; outa += (long)z * sC;
  const int e = e0 + z;
  __shared__ __align__(16) f16 As[2][64 * 64];
  __shared__ __align__(16) f16 Bs[2][64 * 64];
  const int tid = threadIdx.x, wave = tid >> 6, lane = tid & 63;
  const int bid = xcd_swizzle(blockIdx.x, gridDim.x);
  const long m0 = (long)bid * 64;
  f32x4 acc[4] = {};
  const int swz = (tid & 7) ^ ((tid >> 3) & 7);
  const f16* Ag = he1 + (m0 + tid / 8) * K + swz * 8;
  const f16* Bg = Wt + (long)(tid / 8) * K + swz * 8;
  const int wo = wave * 512;
#pragma unroll
  for (int i = 0; i < 2; i++) {
    gld_lds16(Ag + (long)i * 32 * K, &As[0][wo + i * 2048]);
    gld_lds16(Bg + (long)i * 32 * K, &Bs[0][wo + i * 2048]);
  }
  __syncthreads();
  const int nt = K >> 6;
  int cur = 0;
  for (int t = 0; t < nt; ++t) {
    if (t + 1 < nt) {
      const long kt = (long)(t + 1) << 6;
#pragma unroll
      for (int i = 0; i < 2; i++) {
        gld_lds16(Ag + (long)i * 32 * K + kt, &As[cur ^ 1][wo + i * 2048]);
        gld_lds16(Bg + (long)i * 32 * K + kt, &Bs[cur ^ 1][wo + i * 2048]);
      }
    }
#pragma unroll
    for (int kk = 0; kk < 2; kk++) {
      const int rchunk = (kk * 4 + (lane >> 4)) ^ (lane & 7);
      const f16x8 a = *(const f16x8*)&As[cur][(wave * 16 + (lane & 15)) * 64 + rchunk * 8];
#pragma unroll
      for (int ni = 0; ni < 4; ni++) {
        const f16x8 bq = *(const f16x8*)&Bs[cur][(ni * 16 + (lane & 15)) * 64 + rchunk * 8];
        acc[ni] = __builtin_amdgcn_mfma_f32_16x16x32_f16(a, bq, acc[ni], 0, 0, 0);
      }
    }
    __syncthreads();
    cur ^= 1;
  }
  const int r0 = (lane >> 4) * 4, cb = lane & 15;
#pragma unroll
  for (int ni = 0; ni < 4; ni++) {
    const int col = ni * 16 + cb;
    const float sb = scale[col], bb = ebae[col];
    const long row0 = m0 + wave * 16 + r0;
#pragma unroll
    for (int r = 0; r < 4; r++) {
      const long row = row0 + r;
      outa[row * 64 + col] = (acc[ni][r] + bb) * sb * gw[row * 4 + e];
    }
  }
}

// ---------------- combine: out = sum_e a_all[e] (fallback path)
__global__ __launch_bounds__(256) void k_combine(const float* __restrict__ a_all,
                                                 float* __restrict__ out, long n) {
  long i = ((long)blockIdx.x * 256 + threadIdx.x) * 4;
  if (i < n) {
    const float4 v0 = *(const float4*)(a_all + i);
    const float4 v1 = *(const float4*)(a_all + n + i);
    const float4 v2 = *(const float4*)(a_all + 2 * n + i);
    const float4 v3 = *(const float4*)(a_all + 3 * n + i);
    float4 o;
    o.x = v0.x + v1.x + v2.x + v3.x;
    o.y = v0.y + v1.y + v2.y + v3.y;
    o.z = v0.z + v1.z + v2.z + v3.z;
    o.w = v0.w + v1.w + v2.w + v3.w;
    *(float4*)(out + i) = o;
  }
}

// ---------------- launch ----------------
extern "C" void kernel_launch(void* const* d_in, const int* in_sizes, int n_in,
                              void* d_out, int out_size, void* d_ws, size_t ws_size,
                              hipStream_t stream) {
  constexpr int Bn = 16384, S = 512, H0G = 512, H1G = 256, H0E = 1024, H1E = 512, A = 64, E = 4;
  const float* x      = (const float*)d_in[0];
  const float* g_mean = (const float*)d_in[1];
  const float* g_std  = (const float*)d_in[2];
  const float* gW0    = (const float*)d_in[3];
  const float* gb0    = (const float*)d_in[4];
  const float* gW1    = (const float*)d_in[5];
  const float* gb1    = (const float*)d_in[6];
  const float* gWa    = (const float*)d_in[7];
  const float* gba    = (const float*)d_in[8];
  const float* e_mean = (const float*)d_in[9];
  const float* e_std  = (const float*)d_in[10];
  const float* eW0    = (const float*)d_in[11];
  const float* eb0    = (const float*)d_in[12];
  const float* eW1    = (const float*)d_in[13];
  const float* eb1    = (const float*)d_in[14];
  const float* eWa    = (const float*)d_in[15];
  const float* eba    = (const float*)d_in[16];
  const float* scale  = (const float*)d_in[17];
  float* out = (float*)d_out;

  char* p = (char*)d_ws;
  auto alloc = [&](size_t bytes) { char* q = p; p += (bytes + 255) & ~(size_t)255; return q; };
  f16* xh    = (f16*)alloc((size_t)Bn * S * 2);
  float* gw  = (float*)alloc((size_t)Bn * E * 4);
  f16* gW0t  = (f16*)alloc((size_t)S * H0G * 2);
  f16* gW1t  = (f16*)alloc((size_t)H0G * H1G * 2);
  f16* eW0t  = (f16*)alloc((size_t)E * S * H0E * 2);
  f16* eW1t  = (f16*)alloc((size_t)E * H0E * H1E * 2);
  f16* eWat  = (f16*)alloc((size_t)E * H1E * A * 2);
  float* gb0c = (float*)alloc((size_t)H0G * 4);
  float* eb0c = (float*)alloc((size_t)E * H0E * 4);
  f16* h0g   = (f16*)alloc((size_t)Bn * H0G * 2);
  f16* h1g   = (f16*)alloc((size_t)Bn * H1G * 2);   // separate: co-written with he1_g
  const size_t base = (size_t)(p - (char*)d_ws);
  const size_t per_g = ((size_t)Bn * H0E * 2 + 256) + ((size_t)Bn * H1E * 2 + 256);
  const size_t aall_b = (size_t)E * Bn * A * 4 + 256;
  int g = 1;
  if (ws_size >= base + 4 * per_g) g = 4;
  else if (ws_size >= base + 2 * per_g + aall_b) g = 2;
  f16* he0_g = (f16*)alloc((size_t)g * Bn * H0E * 2);  // [g][Bn][1024]
  f16* he1_g = (f16*)alloc((size_t)g * Bn * H1E * 2);  // [g][Bn][512]

  // prep (merged launches)
  k_cvt_x<<<2048, 256, 0, stream>>>(x, xh, (long)Bn * S);
  // W0 family: z=0..3 experts (K=512,N=1024, col-scale e_std), z=4 gating (512x512, g_std)
  k_transpose2<<<dim3(H0E / 32, S / 32, 5), dim3(32, 8), 0, stream>>>(
      eW0, eW0t, e_std, S, H0E, gW0, gW0t, g_std, S, H0G, E);
  // W1 family: z=0..3 experts (K=1024,N=512), z=4 gating (K=512,N=256)
  k_transpose2<<<dim3(H1E / 32, H0E / 32, 5), dim3(32, 8), 0, stream>>>(
      eW1, eW1t, nullptr, H0E, H1E, gW1, gW1t, nullptr, H0G, H1G, E);
  k_transpose<<<dim3(A / 32, H1E / 32, E), dim3(32, 8), 0, stream>>>(eWa, eWat, nullptr, H1E, A);
  // bias fold: y=0..3 experts, y=4 gating
  k_bias_corr2<<<dim3(H0E / 64, 5), dim3(64, 16), 0, stream>>>(
      eW0, eb0, e_mean, e_std, eb0c, S, H0E, gW0, gb0, g_mean, g_std, gb0c, H0G, E);

  constexpr size_t LDSCV = 5 * 128 * 64 * sizeof(f16);      // 80 KiB
  constexpr size_t LDS8P = 2 * 2 * 256 * 64 * sizeof(f16);  // 128 KiB

  if (g == 4) {
    // L0 merged: z=0..3 experts (N=1024 each), z=4 gating L0 (N=512, 2 x-blocks)
    k_gemm_8p<<<dim3(H0E / 256, Bn / 256, 5), 512, LDS8P, stream>>>(
        xh, eW0t, eb0c, he0_g, Bn, S, S, S, H0E,
        0, (long)S * H0E, H0E, (long)Bn * H0E,
        xh, gW0t, gb0c, h0g, S, S, S, H0G, H0G / 256, E);
    // L1 merged: z=0..3 experts (N=512, K=1024), z=4 gating L1 (N=256, K=512, 1 x-block)
    k_gemm_8p<<<dim3(H1E / 256, Bn / 256, 5), 512, LDS8P, stream>>>(
        he0_g, eW1t, eb1, he1_g, Bn, H0E, H0E, H0E, H1E,
        (long)Bn * H0E, (long)H0E * H1E, H1E, (long)Bn * H1E,
        h0g, gW1t, gb1, h1g, H0G, H0G, H0G, H1G, 1, E);
    // gating softmax, then fused head (applies gw per expert segment)
    k_gating_head<<<Bn / 4, 256, 0, stream>>>(h1g, gWa, gba, gw, Bn);
    k_head2<<<dim3(Bn / 64), 256, 0, stream>>>(
        he1_g, eWat, eba, scale, gw, out, (long)Bn * H1E);
  } else {
    float* a_all = (float*)alloc((size_t)E * Bn * A * 4);
    // gating trunk + head (cv kernels)
    k_gemm_cv<<<dim3(H0G / 128, Bn / 128, 1), 256, LDSCV, stream>>>(
        xh, gW0t, gb0c, h0g, Bn, S, S, S, H0G, 0, 0, 0, 0);
    k_gemm_cv<<<dim3(H1G / 128, Bn / 128, 1), 256, LDSCV, stream>>>(
        h0g, gW1t, gb1, h1g, Bn, H0G, H0G, H0G, H1G, 0, 0, 0, 0);
    k_gating_head<<<Bn / 4, 256, 0, stream>>>(h1g, gWa, gba, gw, Bn);
    for (int e0 = 0; e0 < E; e0 += g) {
      k_gemm_cv<<<dim3(H0E / 128, Bn / 128, g), 256, LDSCV, stream>>>(
          xh, eW0t + (size_t)e0 * S * H0E, eb0c + (size_t)e0 * H0E, he0_g,
          Bn, S, S, S, H0E,
          0, (long)S * H0E, H0E, (long)Bn * H0E);
      k_gemm_cv<<<dim3(H1E / 128, Bn / 128, g), 256, LDSCV, stream>>>(
          he0_g, eW1t + (size_t)e0 * H0E * H1E, eb1 + (size_t)e0 * H1E, he1_g,
          Bn, H0E, H0E, H0E, H1E,
          (long)Bn * H0E, (long)H0E * H1E, H1E, (long)Bn * H1E);
      k_head<<<dim3(Bn / 64, 1, g), 256, 0, stream>>>(
          he1_g, eWat + (size_t)e0 * H1E * A, eba + (size_t)e0 * A, scale, gw,
          a_all + (size_t)e0 * Bn * A, e0, H1E,
          (long)Bn * H1E, (long)H1E * A, A, (long)Bn * A);
    }
    k_combine<<<(Bn * A) / 1024, 256, 0, stream>>>(a_all, out, (long)Bn * A);
  }
}

// Round 15
// 294.303 us; speedup vs baseline: 1.0226x; 1.0226x over previous
//
#include <hip/hip_runtime.h>
#include <hip/hip_bf16.h>

typedef _Float16 f16;
typedef _Float16 f16x4 __attribute__((ext_vector_type(4)));
typedef _Float16 f16x8 __attribute__((ext_vector_type(8)));
typedef float f32x4 __attribute__((ext_vector_type(4)));

#define DEV static __device__ __forceinline__

DEV void gld_lds16(const void* g, void* l) {
  __builtin_amdgcn_global_load_lds(
      (const __attribute__((address_space(1))) void*)g,
      (__attribute__((address_space(3))) void*)l, 16, 0, 0);
}

DEV float fast_tanh(float x) {
  float e = __expf(2.0f * x);
  return 1.0f - 2.0f / (e + 1.0f);
}

DEV int xcd_swizzle(int raw, int nwg) {
  return ((nwg & 7) == 0) ? ((raw & 7) * (nwg >> 3) + (raw >> 3)) : raw;
}

// ---------------- x (f32) -> xh (f16) ----------------
__global__ __launch_bounds__(256) void k_cvt_x(const float* __restrict__ x,
                                               f16* __restrict__ xh, long n) {
  long i0 = ((long)blockIdx.x * 256 + threadIdx.x) * 4;
  long stride = (long)gridDim.x * 1024;
  for (long i = i0; i < n; i += stride) {
    const float4 v = *(const float4*)(x + i);
    f16x4 h;
    h.x = (f16)v.x; h.y = (f16)v.y; h.z = (f16)v.z; h.w = (f16)v.w;
    *(f16x4*)(xh + i) = h;
  }
}

// ---------------- W [E][K][N] f32 -> Wt [E][N][K] f16, optional col-scale 1/std[k]
__global__ __launch_bounds__(256) void k_transpose(const float* __restrict__ in,
                                                   f16* __restrict__ out,
                                                   const float* __restrict__ stdv,
                                                   int K_, int N_) {
  __shared__ float tile[32][33];
  const int e = blockIdx.z;
  const float* ine = in + (long)e * K_ * N_;
  f16* oute = out + (long)e * K_ * N_;
  const int n0 = blockIdx.x * 32, k0 = blockIdx.y * 32;
  const int tx = threadIdx.x, ty = threadIdx.y;
#pragma unroll
  for (int j = 0; j < 4; j++)
    tile[ty + j * 8][tx] = ine[(long)(k0 + ty + j * 8) * N_ + n0 + tx];
  __syncthreads();
  const float rs = stdv ? 1.0f / stdv[(long)e * K_ + k0 + tx] : 1.0f;
#pragma unroll
  for (int j = 0; j < 4; j++)
    oute[(long)(n0 + ty + j * 8) * K_ + k0 + tx] = (f16)(tile[tx][ty + j * 8] * rs);
}

// ---------------- corrected bias: outb[e][h] = b[e][h] - sum_s (mean/std)[e][s]*W[e][s][h]
__global__ __launch_bounds__(1024) void k_bias_corr(const float* __restrict__ W,
                                                    const float* __restrict__ b,
                                                    const float* __restrict__ mean,
                                                    const float* __restrict__ stdv,
                                                    float* __restrict__ outb,
                                                    int S_, int H_) {
  __shared__ float red[16][64];
  const int e = blockIdx.y;
  const float* We = W + (long)e * S_ * H_;
  const float* me = mean + (long)e * S_;
  const float* se = stdv + (long)e * S_;
  const int h = blockIdx.x * 64 + threadIdx.x;
  const int sl = threadIdx.y;
  float acc = 0.0f;
#pragma unroll 4
  for (int s = sl; s < S_; s += 16) acc += (me[s] / se[s]) * We[(long)s * H_ + h];
  red[sl][threadIdx.x] = acc;
  __syncthreads();
  if (sl == 0) {
    float a = 0.0f;
#pragma unroll
    for (int j = 0; j < 16; j++) a += red[j][threadIdx.x];
    outb[(long)e * H_ + h] = b[(long)e * H_ + h] - a;
  }
}

// ---------------- 128x128 GEMM, BK=64, counted-vmcnt pipeline (R11, proven).
__global__ __launch_bounds__(256) void k_gemm_cv(
    const f16* __restrict__ A, const f16* __restrict__ Bt,
    const float* __restrict__ bias, f16* __restrict__ C,
    int M, int K, int lda, int ldb, int ldc,
    long sA, long sB, long sBias, long sC) {
  A += (long)blockIdx.z * sA; Bt += (long)blockIdx.z * sB;
  bias += (long)blockIdx.z * sBias; C += (long)blockIdx.z * sC;
  extern __shared__ __align__(16) f16 lds[];  // A: 3*8192 f16, B at 24576 + 2*8192
  const int tid = threadIdx.x, wave = tid >> 6, lane = tid & 63;
  const int nwg = gridDim.x * gridDim.y;
  const int logical = xcd_swizzle(blockIdx.y * gridDim.x + blockIdx.x, nwg);
  const int bx = logical % gridDim.x, by = logical / gridDim.x;
  const int m0 = by * 128, n0 = bx * 128;
  const int wr = wave >> 1, wc = wave & 1;
  f32x4 acc[4][4] = {};
  const int swz = (tid & 7) ^ ((tid >> 3) & 7);
  const f16* Ag = A + (long)(m0 + (tid >> 3)) * lda + swz * 8;
  const f16* Bg = Bt + (long)(n0 + (tid >> 3)) * ldb + swz * 8;
  const int wo = wave * 512;

#define STG_A(bufi, tile)                                         \
  { f16* _d = lds + (bufi) * 8192 + wo;                           \
    const long _k = (long)(tile) << 6;                            \
    gld_lds16(Ag + _k, _d);                                       \
    gld_lds16(Ag + (long)32 * lda + _k, _d + 2048);               \
    gld_lds16(Ag + (long)64 * lda + _k, _d + 4096);               \
    gld_lds16(Ag + (long)96 * lda + _k, _d + 6144); }
#define STG_B(bufi, tile)                                         \
  { f16* _d = lds + 24576 + (bufi) * 8192 + wo;                   \
    const long _k = (long)(tile) << 6;                            \
    gld_lds16(Bg + _k, _d);                                       \
    gld_lds16(Bg + (long)32 * ldb + _k, _d + 2048);               \
    gld_lds16(Bg + (long)64 * ldb + _k, _d + 4096);               \
    gld_lds16(Bg + (long)96 * ldb + _k, _d + 6144); }

  const int nt = K >> 6;  // nt >= 2
  STG_A(0, 0)
  STG_B(0, 0)
  STG_A(1, 1)
  asm volatile("s_waitcnt vmcnt(4)" ::: "memory");
  __builtin_amdgcn_s_barrier();
  asm volatile("" ::: "memory");

  for (int t = 0; t < nt; ++t) {
    if (t + 1 < nt) STG_B((t + 1) & 1, t + 1)
    if (t + 2 < nt) STG_A((t + 2) % 3, t + 2)
    const f16* Abuf = lds + (t % 3) * 8192;
    const f16* Bbuf = lds + 24576 + (t & 1) * 8192;
#pragma unroll
    for (int kk = 0; kk < 2; kk++) {
      f16x8 af[4], bfr[4];
      const int rchunk = (kk * 4 + (lane >> 4)) ^ (lane & 7);
#pragma unroll
      for (int mi = 0; mi < 4; mi++)
        af[mi] = *(const f16x8*)&Abuf[(wr * 64 + mi * 16 + (lane & 15)) * 64 + rchunk * 8];
#pragma unroll
      for (int ni = 0; ni < 4; ni++)
        bfr[ni] = *(const f16x8*)&Bbuf[(wc * 64 + ni * 16 + (lane & 15)) * 64 + rchunk * 8];
#pragma unroll
      for (int mi = 0; mi < 4; mi++)
#pragma unroll
        for (int ni = 0; ni < 4; ni++)
          acc[mi][ni] = __builtin_amdgcn_mfma_f32_16x16x32_f16(af[mi], bfr[ni], acc[mi][ni], 0, 0, 0);
    }
    if (t + 2 < nt) {
      asm volatile("s_waitcnt vmcnt(4)" ::: "memory");
    } else {
      asm volatile("s_waitcnt vmcnt(0)" ::: "memory");
    }
    __builtin_amdgcn_s_barrier();
    asm volatile("" ::: "memory");
  }
#undef STG_A
#undef STG_B

  const int r0 = (lane >> 4) * 4, cb = lane & 15;
#pragma unroll
  for (int ni = 0; ni < 4; ni++) {
    const int col = n0 + wc * 64 + ni * 16 + cb;
    const float bc = bias[col];
#pragma unroll
    for (int mi = 0; mi < 4; mi++) {
      const int row = m0 + wr * 64 + mi * 16 + r0;
#pragma unroll
      for (int r = 0; r < 4; r++)
        C[(long)(row + r) * ldc + col] = (f16)fast_tanh(acc[mi][ni][r] + bc);
    }
  }
}

// ---------------- 256x256 8-phase GEMM (experts). 512 thr = 8 waves (2M x 4N),
// wave tile 128x64, BK=64, 2-buffer 128 KiB LDS. 4 phases per K-tile j:
//   q0: read af(kk0)+bfr01(kk0) | stage A1[j+1]   -> MFMA ni01
//   q1: read bfr23(kk0)         | stage B0[j+1]   -> MFMA ni23
//   q2: read af(kk1)+bfr01(kk1) | stage B1[j+1]   -> MFMA ni01
//   q3: read bfr23(kk1)         | stage A0[j+2]   -> MFMA ni23; vmcnt(2|0)
// Invariants: stage targets sealed >=1 barrier before issue; vmcnt(2) at q3
// forces K-tile j+1 fully landed (only A0[j+2] in flight).
// Swizzle = R4 chunk-XOR (2-way, free). C = tanh(A@Bt^T + bias). K%64==0, nt>=2.
__global__ __launch_bounds__(512, 2) void k_gemm_8p(
    const f16* __restrict__ A, const f16* __restrict__ Bt,
    const float* __restrict__ bias, f16* __restrict__ C,
    int M, int K, int lda, int ldb, int ldc,
    long sA, long sB, long sBias, long sC) {
  A += (long)blockIdx.z * sA; Bt += (long)blockIdx.z * sB;
  bias += (long)blockIdx.z * sBias; C += (long)blockIdx.z * sC;
  extern __shared__ __align__(16) f16 lds[];  // buf b: A at b*32768 (256x64), B at +16384
  const int tid = threadIdx.x, wave = tid >> 6, lane = tid & 63;
  const int nwg = gridDim.x * gridDim.y;
  const int logical = xcd_swizzle(blockIdx.y * gridDim.x + blockIdx.x, nwg);
  const int bx = logical % gridDim.x, by = logical / gridDim.x;
  const int m0 = by * 256, n0 = bx * 256;
  const int wr = wave >> 2, wc = wave & 3;
  f32x4 acc[8][4] = {};

  const int swz = (tid & 7) ^ ((tid >> 3) & 7);
  const f16* Ag = A + (long)(m0 + (tid >> 3)) * lda + swz * 8;
  const f16* Bg = Bt + (long)(n0 + (tid >> 3)) * ldb + swz * 8;
  const int tdst = tid * 8;  // f16 units within an 8KB call slab

  const int rc0 = (lane >> 4) ^ (lane & 7);        // kk0 physical chunk
  const int rc1 = (4 + (lane >> 4)) ^ (lane & 7);  // kk1
  int aoff[8], boff[4];
#pragma unroll
  for (int mi = 0; mi < 8; mi++) aoff[mi] = (wr * 128 + mi * 16 + (lane & 15)) * 64;
#pragma unroll
  for (int ni = 0; ni < 4; ni++) boff[ni] = 16384 + (wc * 64 + ni * 16 + (lane & 15)) * 64;

#define STG_A(jt, h)                                                          \
  { f16* _d = lds + ((jt) & 1) * 32768 + (h) * 8192 + tdst;                   \
    const long _k = (long)(jt) << 6;                                          \
    gld_lds16(Ag + (long)((h) * 128) * lda + _k, _d);                         \
    gld_lds16(Ag + (long)((h) * 128 + 64) * lda + _k, _d + 4096); }
#define STG_B(jt, h)                                                          \
  { f16* _d = lds + ((jt) & 1) * 32768 + 16384 + (h) * 8192 + tdst;           \
    const long _k = (long)(jt) << 6;                                          \
    gld_lds16(Bg + (long)((h) * 128) * ldb + _k, _d);                         \
    gld_lds16(Bg + (long)((h) * 128 + 64) * ldb + _k, _d + 4096); }
#define LOAD_A(b, rc)                                                         \
  _Pragma("unroll") for (int mi = 0; mi < 8; mi++)                            \
      af[mi] = *(const f16x8*)&lds[(b) * 32768 + aoff[mi] + (rc) * 8];
#define LOAD_B(b, ni, rc)                                                     \
  bfr[ni] = *(const f16x8*)&lds[(b) * 32768 + boff[ni] + (rc) * 8];
#define MMA2(nA, nB)                                                          \
  __builtin_amdgcn_s_setprio(1);                                              \
  _Pragma("unroll") for (int mi = 0; mi < 8; mi++) {                          \
    acc[mi][nA] = __builtin_amdgcn_mfma_f32_16x16x32_f16(af[mi], bfr[nA], acc[mi][nA], 0, 0, 0); \
    acc[mi][nB] = __builtin_amdgcn_mfma_f32_16x16x32_f16(af[mi], bfr[nB], acc[mi][nB], 0, 0, 0); \
  }                                                                           \
  __builtin_amdgcn_s_setprio(0);
#define BAR()                                                                 \
  __builtin_amdgcn_s_barrier();                                               \
  asm volatile("" ::: "memory")
#define WAITL()                                                               \
  asm volatile("s_waitcnt lgkmcnt(0)" ::: "memory");                          \
  __builtin_amdgcn_sched_barrier(0)

  const int nt = K >> 6;  // nt >= 2

  STG_A(0, 0) STG_A(0, 1) STG_B(0, 0) STG_B(0, 1)
  STG_A(1, 0)
  asm volatile("s_waitcnt vmcnt(2)" ::: "memory");
  BAR();

  f16x8 af[8], bfr[4];
  for (int j = 0; j < nt; ++j) {
    const int b = j & 1;
    LOAD_A(b, rc0) LOAD_B(b, 0, rc0) LOAD_B(b, 1, rc0)
    if (j + 1 < nt) STG_A(j + 1, 1)
    BAR(); WAITL(); MMA2(0, 1) BAR();
    LOAD_B(b, 2, rc0) LOAD_B(b, 3, rc0)
    if (j + 1 < nt) STG_B(j + 1, 0)
    BAR(); WAITL(); MMA2(2, 3) BAR();
    LOAD_A(b, rc1) LOAD_B(b, 0, rc1) LOAD_B(b, 1, rc1)
    if (j + 1 < nt) STG_B(j + 1, 1)
    BAR(); WAITL(); MMA2(0, 1) BAR();
    LOAD_B(b, 2, rc1) LOAD_B(b, 3, rc1)
    if (j + 2 < nt) STG_A(j + 2, 0)
    BAR(); WAITL(); MMA2(2, 3)
    if (j + 1 < nt) {
      if (j + 2 < nt) {
        asm volatile("s_waitcnt vmcnt(2)" ::: "memory");
      } else {
        asm volatile("s_waitcnt vmcnt(0)" ::: "memory");
      }
    }
    BAR();
  }
#undef STG_A
#undef STG_B
#undef LOAD_A
#undef LOAD_B
#undef MMA2
#undef BAR
#undef WAITL

  const int r0 = (lane >> 4) * 4, cb = lane & 15;
  float bcv[4];
#pragma unroll
  for (int ni = 0; ni < 4; ni++) bcv[ni] = bias[n0 + wc * 64 + ni * 16 + cb];
#pragma unroll
  for (int mi = 0; mi < 8; mi++) {
#pragma unroll
    for (int r = 0; r < 4; r++) {
      const long row = m0 + wr * 128 + mi * 16 + r0 + r;
#pragma unroll
      for (int ni = 0; ni < 4; ni++) {
        const int col = n0 + wc * 64 + ni * 16 + cb;
        C[row * (long)ldc + col] = (f16)fast_tanh(acc[mi][ni][r] + bcv[ni]);
      }
    }
  }
}

// ---------------- gating head: logits = h1 @ gWa + gba; softmax over 4 -> gw [B,4] f32
__global__ __launch_bounds__(256) void k_gating_head(const f16* __restrict__ h1,
                                                     const float* __restrict__ gWa,
                                                     const float* __restrict__ gba,
                                                     float* __restrict__ gw, int B_) {
  const int b = blockIdx.x * 4 + (threadIdx.x >> 6);
  const int lane = threadIdx.x & 63;
  const f16x4 hv = *(const f16x4*)&h1[(long)b * 256 + lane * 4];
  float s0 = 0, s1 = 0, s2 = 0, s3 = 0;
#pragma unroll
  for (int j = 0; j < 4; j++) {
    const float hh = (float)hv[j];
    const float4 wr4 = *(const float4*)&gWa[(lane * 4 + j) * 4];
    s0 += hh * wr4.x; s1 += hh * wr4.y; s2 += hh * wr4.z; s3 += hh * wr4.w;
  }
#pragma unroll
  for (int off = 32; off >= 1; off >>= 1) {
    s0 += __shfl_xor(s0, off);
    s1 += __shfl_xor(s1, off);
    s2 += __shfl_xor(s2, off);
    s3 += __shfl_xor(s3, off);
  }
  const float l0 = s0 + gba[0], l1 = s1 + gba[1], l2 = s2 + gba[2], l3 = s3 + gba[3];
  float mx = fmaxf(fmaxf(l0, l1), fmaxf(l2, l3));
  const float e0 = __expf(l0 - mx), e1 = __expf(l1 - mx), e2 = __expf(l2 - mx), e3 = __expf(l3 - mx);
  const float inv = 1.0f / (e0 + e1 + e2 + e3);
  if (lane == 0) {
    float4 o; o.x = e0 * inv; o.y = e1 * inv; o.z = e2 * inv; o.w = e3 * inv;
    *(float4*)&gw[(long)b * 4] = o;
  }
}

// ---------------- fused head (g==4): out[b,a] = [sum_e gw[b,e]*((he1_e@Wt_e^T)[b,a]
//                  + eba[e,a])] * scale[a]; gw applied in-register per expert segment.
__global__ __launch_bounds__(256) void k_head2(const f16* __restrict__ he1,
                                               const f16* __restrict__ Wt,
                                               const float* __restrict__ eba,
                                               const float* __restrict__ scale,
                                               const float* __restrict__ gw,
                                               float* __restrict__ out,
                                               long sA) {
  constexpr int K = 512;
  __shared__ __align__(16) f16 As[2][64 * 64];
  __shared__ __align__(16) f16 Bs[2][64 * 64];
  const int tid = threadIdx.x, wave = tid >> 6, lane = tid & 63;
  const int bid = xcd_swizzle(blockIdx.x, gridDim.x);
  const long m0 = (long)bid * 64;
  const int swz = (tid & 7) ^ ((tid >> 3) & 7);
  const f16* Ag = he1 + (m0 + tid / 8) * K + swz * 8;
  const f16* Bg = Wt + (long)(tid / 8) * K + swz * 8;
  const int wo = wave * 512;
  const int r0 = (lane >> 4) * 4, cb = lane & 15;
  float4 gwv[4];
#pragma unroll
  for (int r = 0; r < 4; r++)
    gwv[r] = *(const float4*)&gw[(m0 + wave * 16 + r0 + r) * 4];
  f32x4 osum[4] = {};
  f32x4 acc[4] = {};

#pragma unroll
  for (int i = 0; i < 2; i++) {
    gld_lds16(Ag + (long)i * 32 * K, &As[0][wo + i * 2048]);
    gld_lds16(Bg + (long)i * 32 * K, &Bs[0][wo + i * 2048]);
  }
  __syncthreads();
  int cur = 0;
#pragma unroll
  for (int e = 0; e < 4; e++) {
    for (int kt = 0; kt < 8; ++kt) {
      const int s = e * 8 + kt;
      if (s + 1 < 32) {
        const int sn = s + 1;
        const long ae = (long)(sn >> 3) * sA + ((sn & 7) << 6);
        const long be = (long)(sn >> 3) * (64 * K) + ((sn & 7) << 6);
#pragma unroll
        for (int i = 0; i < 2; i++) {
          gld_lds16(Ag + ae + (long)i * 32 * K, &As[cur ^ 1][wo + i * 2048]);
          gld_lds16(Bg + be + (long)i * 32 * K, &Bs[cur ^ 1][wo + i * 2048]);
        }
      }
#pragma unroll
      for (int kk = 0; kk < 2; kk++) {
        const int rchunk = (kk * 4 + (lane >> 4)) ^ (lane & 7);
        const f16x8 a = *(const f16x8*)&As[cur][(wave * 16 + (lane & 15)) * 64 + rchunk * 8];
#pragma unroll
        for (int ni = 0; ni < 4; ni++) {
          const f16x8 bq = *(const f16x8*)&Bs[cur][(ni * 16 + (lane & 15)) * 64 + rchunk * 8];
          acc[ni] = __builtin_amdgcn_mfma_f32_16x16x32_f16(a, bq, acc[ni], 0, 0, 0);
        }
      }
      __syncthreads();
      cur ^= 1;
    }
#pragma unroll
    for (int ni = 0; ni < 4; ni++)
#pragma unroll
      for (int r = 0; r < 4; r++) {
        const float ge = (e == 0) ? gwv[r].x : (e == 1) ? gwv[r].y
                        : (e == 2) ? gwv[r].z : gwv[r].w;
        osum[ni][r] += ge * acc[ni][r];
        acc[ni][r] = 0.0f;
      }
  }

#pragma unroll
  for (int ni = 0; ni < 4; ni++) {
    const int col = ni * 16 + cb;
    const float sc = scale[col];
#pragma unroll
    for (int r = 0; r < 4; r++) {
      const long row = m0 + wave * 16 + r0 + r;
      const float b4 = gwv[r].x * eba[col] + gwv[r].y * eba[64 + col] +
                       gwv[r].z * eba[128 + col] + gwv[r].w * eba[192 + col];
      out[row * 64 + col] = (osum[ni][r] + b4) * sc;
    }
  }
}

// ---------------- per-expert head (fallback path)
__global__ __launch_bounds__(256) void k_head(const f16* __restrict__ he1,
                                              const f16* __restrict__ Wt,
                                              const float* __restrict__ ebae,
                                              const float* __restrict__ scale,
                                              const float* __restrict__ gw,
                                              float* __restrict__ outa,
                                              int e0, int K,
                                              long sA, long sB, long sBias, long sC) {
  const int z = blockIdx.z;
  he1 += (long)z * sA; Wt += (long)z * sB; ebae += (long)z * sBias; outa += (long)z * sC;
  const int e = e0 + z;
  __shared__ __align__(16) f16 As[2][64 * 64];
  __shared__ __align__(16) f16 Bs[2][64 * 64];
  const int tid = threadIdx.x, wave = tid >> 6, lane = tid & 63;
  const int bid = xcd_swizzle(blockIdx.x, gridDim.x);
  const long m0 = (long)bid * 64;
  f32x4 acc[4] = {};
  const int swz = (tid & 7) ^ ((tid >> 3) & 7);
  const f16* Ag = he1 + (m0 + tid / 8) * K + swz * 8;
  const f16* Bg = Wt + (long)(tid / 8) * K + swz * 8;
  const int wo = wave * 512;
#pragma unroll
  for (int i = 0; i < 2; i++) {
    gld_lds16(Ag + (long)i * 32 * K, &As[0][wo + i * 2048]);
    gld_lds16(Bg + (long)i * 32 * K, &Bs[0][wo + i * 2048]);
  }
  __syncthreads();
  const int nt = K >> 6;
  int cur = 0;
  for (int t = 0; t < nt; ++t) {
    if (t + 1 < nt) {
      const long kt = (long)(t + 1) << 6;
#pragma unroll
      for (int i = 0; i < 2; i++) {
        gld_lds16(Ag + (long)i * 32 * K + kt, &As[cur ^ 1][wo + i * 2048]);
        gld_lds16(Bg + (long)i * 32 * K + kt, &Bs[cur ^ 1][wo + i * 2048]);
      }
    }
#pragma unroll
    for (int kk = 0; kk < 2; kk++) {
      const int rchunk = (kk * 4 + (lane >> 4)) ^ (lane & 7);
      const f16x8 a = *(const f16x8*)&As[cur][(wave * 16 + (lane & 15)) * 64 + rchunk * 8];
#pragma unroll
      for (int ni = 0; ni < 4; ni++) {
        const f16x8 bq = *(const f16x8*)&Bs[cur][(ni * 16 + (lane & 15)) * 64 + rchunk * 8];
        acc[ni] = __builtin_amdgcn_mfma_f32_16x16x32_f16(a, bq, acc[ni], 0, 0, 0);
      }
    }
    __syncthreads();
    cur ^= 1;
  }
  const int r0 = (lane >> 4) * 4, cb = lane & 15;
#pragma unroll
  for (int ni = 0; ni < 4; ni++) {
    const int col = ni * 16 + cb;
    const float sb = scale[col], bb = ebae[col];
    const long row0 = m0 + wave * 16 + r0;
#pragma unroll
    for (int r = 0; r < 4; r++) {
      const long row = row0 + r;
      outa[row * 64 + col] = (acc[ni][r] + bb) * sb * gw[row * 4 + e];
    }
  }
}

// ---------------- combine: out = sum_e a_all[e] (fallback path)
__global__ __launch_bounds__(256) void k_combine(const float* __restrict__ a_all,
                                                 float* __restrict__ out, long n) {
  long i = ((long)blockIdx.x * 256 + threadIdx.x) * 4;
  if (i < n) {
    const float4 v0 = *(const float4*)(a_all + i);
    const float4 v1 = *(const float4*)(a_all + n + i);
    const float4 v2 = *(const float4*)(a_all + 2 * n + i);
    const float4 v3 = *(const float4*)(a_all + 3 * n + i);
    float4 o;
    o.x = v0.x + v1.x + v2.x + v3.x;
    o.y = v0.y + v1.y + v2.y + v3.y;
    o.z = v0.z + v1.z + v2.z + v3.z;
    o.w = v0.w + v1.w + v2.w + v3.w;
    *(float4*)(out + i) = o;
  }
}

// ---------------- launch ----------------
extern "C" void kernel_launch(void* const* d_in, const int* in_sizes, int n_in,
                              void* d_out, int out_size, void* d_ws, size_t ws_size,
                              hipStream_t stream) {
  constexpr int Bn = 16384, S = 512, H0G = 512, H1G = 256, H0E = 1024, H1E = 512, A = 64, E = 4;
  const float* x      = (const float*)d_in[0];
  const float* g_mean = (const float*)d_in[1];
  const float* g_std  = (const float*)d_in[2];
  const float* gW0    = (const float*)d_in[3];
  const float* gb0    = (const float*)d_in[4];
  const float* gW1    = (const float*)d_in[5];
  const float* gb1    = (const float*)d_in[6];
  const float* gWa    = (const float*)d_in[7];
  const float* gba    = (const float*)d_in[8];
  const float* e_mean = (const float*)d_in[9];
  const float* e_std  = (const float*)d_in[10];
  const float* eW0    = (const float*)d_in[11];
  const float* eb0    = (const float*)d_in[12];
  const float* eW1    = (const float*)d_in[13];
  const float* eb1    = (const float*)d_in[14];
  const float* eWa    = (const float*)d_in[15];
  const float* eba    = (const float*)d_in[16];
  const float* scale  = (const float*)d_in[17];
  float* out = (float*)d_out;

  char* p = (char*)d_ws;
  auto alloc = [&](size_t bytes) { char* q = p; p += (bytes + 255) & ~(size_t)255; return q; };
  f16* xh    = (f16*)alloc((size_t)Bn * S * 2);
  float* gw  = (float*)alloc((size_t)Bn * E * 4);
  float* a_all = (float*)alloc((size_t)E * Bn * A * 4);
  f16* gW0t  = (f16*)alloc((size_t)S * H0G * 2);
  f16* gW1t  = (f16*)alloc((size_t)H0G * H1G * 2);
  f16* eW0t  = (f16*)alloc((size_t)E * S * H0E * 2);
  f16* eW1t  = (f16*)alloc((size_t)E * H0E * H1E * 2);
  f16* eWat  = (f16*)alloc((size_t)E * H1E * A * 2);
  float* gb0c = (float*)alloc((size_t)H0G * 4);
  float* eb0c = (float*)alloc((size_t)E * H0E * 4);
  f16* h0g   = (f16*)alloc((size_t)Bn * H0G * 2);
  const size_t base = (size_t)(p - (char*)d_ws);
  const size_t per_g = ((size_t)Bn * H0E * 2 + 256) + ((size_t)Bn * H1E * 2 + 256);
  int g = 1;
  if (ws_size >= base + 4 * per_g) g = 4;
  else if (ws_size >= base + 2 * per_g) g = 2;
  f16* he0_g = (f16*)alloc((size_t)g * Bn * H0E * 2);  // [g][Bn][1024]
  f16* he1_g = (f16*)alloc((size_t)g * Bn * H1E * 2);  // [g][Bn][512]
  f16* h1g = he1_g;  // gating h1 aliases he1 scratch (read before expert L1 writes)

  // prep
  k_cvt_x<<<2048, 256, 0, stream>>>(x, xh, (long)Bn * S);
  k_transpose<<<dim3(H0G / 32, S / 32, 1), dim3(32, 8), 0, stream>>>(gW0, gW0t, g_std, S, H0G);
  k_transpose<<<dim3(H1G / 32, H0G / 32, 1), dim3(32, 8), 0, stream>>>(gW1, gW1t, nullptr, H0G, H1G);
  k_transpose<<<dim3(H0E / 32, S / 32, E), dim3(32, 8), 0, stream>>>(eW0, eW0t, e_std, S, H0E);
  k_transpose<<<dim3(H1E / 32, H0E / 32, E), dim3(32, 8), 0, stream>>>(eW1, eW1t, nullptr, H0E, H1E);
  k_transpose<<<dim3(A / 32, H1E / 32, E), dim3(32, 8), 0, stream>>>(eWa, eWat, nullptr, H1E, A);
  k_bias_corr<<<dim3(H0G / 64, 1), dim3(64, 16), 0, stream>>>(gW0, gb0, g_mean, g_std, gb0c, S, H0G);
  k_bias_corr<<<dim3(H0E / 64, E), dim3(64, 16), 0, stream>>>(eW0, eb0, e_mean, e_std, eb0c, S, H0E);

  constexpr size_t LDSCV = 5 * 128 * 64 * sizeof(f16);    // 80 KiB
  constexpr size_t LDS8P = 2 * 2 * 256 * 64 * sizeof(f16);  // 128 KiB

  // gating trunk + softmax head (proven counted-vmcnt 128^2 kernel)
  k_gemm_cv<<<dim3(H0G / 128, Bn / 128, 1), 256, LDSCV, stream>>>(
      xh, gW0t, gb0c, h0g, Bn, S, S, S, H0G, 0, 0, 0, 0);
  k_gemm_cv<<<dim3(H1G / 128, Bn / 128, 1), 256, LDSCV, stream>>>(
      h0g, gW1t, gb1, h1g, Bn, H0G, H0G, H0G, H1G, 0, 0, 0, 0);
  k_gating_head<<<Bn / 4, 256, 0, stream>>>(h1g, gWa, gba, gw, Bn);

  if (g == 4) {
    // expert L0: z=4, shared A (xh), 256^2 8-phase
    k_gemm_8p<<<dim3(H0E / 256, Bn / 256, 4), 512, LDS8P, stream>>>(
        xh, eW0t, eb0c, he0_g, Bn, S, S, S, H0E,
        0, (long)S * H0E, H0E, (long)Bn * H0E);
    // expert L1: z=4, K=1024 (unscaled; gw applied in k_head2)
    k_gemm_8p<<<dim3(H1E / 256, Bn / 256, 4), 512, LDS8P, stream>>>(
        he0_g, eW1t, eb1, he1_g, Bn, H0E, H0E, H0E, H1E,
        (long)Bn * H0E, (long)H0E * H1E, H1E, (long)Bn * H1E);
    // fused head over concat-K (4 x 512), writes out directly
    k_head2<<<dim3(Bn / 64), 256, 0, stream>>>(
        he1_g, eWat, eba, scale, gw, out, (long)Bn * H1E);
  } else {
    for (int e0 = 0; e0 < E; e0 += g) {
      k_gemm_cv<<<dim3(H0E / 128, Bn / 128, g), 256, LDSCV, stream>>>(
          xh, eW0t + (size_t)e0 * S * H0E, eb0c + (size_t)e0 * H0E, he0_g,
          Bn, S, S, S, H0E,
          0, (long)S * H0E, H0E, (long)Bn * H0E);
      k_gemm_cv<<<dim3(H1E / 128, Bn / 128, g), 256, LDSCV, stream>>>(
          he0_g, eW1t + (size_t)e0 * H0E * H1E, eb1 + (size_t)e0 * H1E, he1_g,
          Bn, H0E, H0E, H0E, H1E,
          (long)Bn * H0E, (long)H0E * H1E, H1E, (long)Bn * H1E);
      k_head<<<dim3(Bn / 64, 1, g), 256, 0, stream>>>(
          he1_g, eWat + (size_t)e0 * H1E * A, eba + (size_t)e0 * A, scale, gw,
          a_all + (size_t)e0 * Bn * A, e0, H1E,
          (long)Bn * H1E, (long)H1E * A, A, (long)Bn * A);
    }
    k_combine<<<(Bn * A) / 1024, 256, 0, stream>>>(a_all, out, (long)Bn * A);
  }
}